// Round 1
// baseline (564.024 us; speedup 1.0000x reference)
//
#include <hip/hip_runtime.h>

// SimAttn: out = softmax(1000*softmax(QK^T/sqrt(dk))) @ V, fp32 I/O.
// Two-pass flash structure:
//   pass 1: bf16 MFMA QK^T -> per-row (m, l) online stats
//   pass 2: split-bf16 (hi+lo, 3 MFMA) QK^T -> w = exp(u*(exp(s-m)-1)),
//           u = 1000/l  (max exponent is exactly 0 -> overflow-safe),
//           PV via bf16 MFMA with unnormalized w; divide by sum(w) at end.
// m cancels analytically between u and exp(s-m), so pass-1 precision only
// affects l (relative err ~3e-4 -> weight err ~3e-3: negligible).

typedef __attribute__((ext_vector_type(4))) float f32x4;
typedef __attribute__((ext_vector_type(8))) short s16x8;
typedef __attribute__((ext_vector_type(4))) short s16x4;

#define NB 4
#define T_ 2048
#define D_ 1024
#define NH 8
#define DK 128
#define BQ 64
#define KB 64
#define NKC (T_ / KB)
#define SCALE 0.08838834764831845f  // 1/sqrt(128)

__device__ __forceinline__ unsigned short f2bf(float x) {
  unsigned u = __builtin_bit_cast(unsigned, x);
  u += 0x7fffu + ((u >> 16) & 1u);           // round-to-nearest-even
  return (unsigned short)(u >> 16);
}
__device__ __forceinline__ float bf2f(unsigned short h) {
  unsigned u = ((unsigned)h) << 16;
  return __builtin_bit_cast(float, u);
}

__global__ __launch_bounds__(256) void simattn_fused(
    const float* __restrict__ Qg, const float* __restrict__ Kg,
    const float* __restrict__ Vg, float* __restrict__ Og) {
  // K tiles row-major [key][d] bf16 with 16B XOR swizzle; V transposed [d][key].
  __shared__ __align__(16) unsigned short khi[KB][DK];   // 16 KB
  __shared__ __align__(16) unsigned short klo[KB][DK];   // 16 KB
  __shared__ __align__(16) unsigned short vts[DK][KB];   // 16 KB
  __shared__ __align__(16) unsigned short wls[BQ][KB];   //  8 KB

  const int tid  = threadIdx.x;
  const int wid  = tid >> 6;
  const int lane = tid & 63;
  const int lr   = lane & 15;   // A-row / B-col / C-col within 16
  const int lg   = lane >> 4;   // k-slot group; C-row group

  const int blk  = blockIdx.x;
  const int qblk = blk & (T_ / BQ - 1);
  const int h    = (blk >> 5) & (NH - 1);
  const int b    = blk >> 8;

  const int q0 = qblk * BQ;
  const size_t bh = (size_t)b * (T_ * D_) + (size_t)h * DK;

  // ---- Q fragments (split bf16 hi/lo), kept in registers --------------------
  s16x8 qhi[4], qlo[4];
  {
    const float* qp = Qg + bh + (size_t)(q0 + wid * 16 + lr) * D_;
#pragma unroll
    for (int s = 0; s < 4; ++s) {
      const int d0 = s * 32 + lg * 8;
      f32x4 x0 = *(const f32x4*)(qp + d0);
      f32x4 x1 = *(const f32x4*)(qp + d0 + 4);
#pragma unroll
      for (int i = 0; i < 8; ++i) {
        float x = (i < 4) ? x0[i] : x1[i - 4];
        unsigned short hb = f2bf(x);
        qhi[s][i] = (short)hb;
        qlo[s][i] = (short)f2bf(x - bf2f(hb));
      }
    }
  }

  // ---- pass 1: per-row (m, l) via online softmax stats ----------------------
  float m_run[4], l_run[4];
#pragma unroll
  for (int r = 0; r < 4; ++r) { m_run[r] = -3.0e38f; l_run[r] = 0.f; }

  for (int kc = 0; kc < NKC; ++kc) {
    const int k0 = kc * KB;
    __syncthreads();
    {
      const float* kp = Kg + bh + (size_t)k0 * D_;
#pragma unroll
      for (int p = 0; p < 8; ++p) {
        const int j = tid + p * 256;
        const int row = j >> 5, c4 = j & 31;
        f32x4 v = *(const f32x4*)(kp + (size_t)row * D_ + c4 * 4);
        s16x4 hv;
#pragma unroll
        for (int i = 0; i < 4; ++i) hv[i] = (short)f2bf(v[i]);
        const int e = (c4 * 4) ^ ((row & 7) << 3);
        *(s16x4*)&khi[row][e] = hv;
      }
    }
    __syncthreads();

    f32x4 sc[4];
#pragma unroll
    for (int nt = 0; nt < 4; ++nt) sc[nt] = (f32x4){0.f, 0.f, 0.f, 0.f};
#pragma unroll
    for (int s = 0; s < 4; ++s) {
#pragma unroll
      for (int nt = 0; nt < 4; ++nt) {
        const int kr = nt * 16 + lr;
        const int e = (s * 32 + lg * 8) ^ ((kr & 7) << 3);
        s16x8 bh16 = *(const s16x8*)&khi[kr][e];
        sc[nt] = __builtin_amdgcn_mfma_f32_16x16x32_bf16(qhi[s], bh16, sc[nt], 0, 0, 0);
      }
    }
#pragma unroll
    for (int r = 0; r < 4; ++r) {
      const float s0 = sc[0][r] * SCALE, s1 = sc[1][r] * SCALE;
      const float s2 = sc[2][r] * SCALE, s3 = sc[3][r] * SCALE;
      const float mx = fmaxf(fmaxf(s0, s1), fmaxf(s2, s3));
      const float mn = fmaxf(m_run[r], mx);
      const float add = __expf(s0 - mn) + __expf(s1 - mn) + __expf(s2 - mn) + __expf(s3 - mn);
      l_run[r] = l_run[r] * __expf(m_run[r] - mn) + add;
      m_run[r] = mn;
    }
  }

  // merge stats across the 16 column-lanes (lane bits 0..3)
  float u_[4];
#pragma unroll
  for (int r = 0; r < 4; ++r) {
    float m = m_run[r], l = l_run[r];
#pragma unroll
    for (int off = 1; off < 16; off <<= 1) {
      const float m2 = __shfl_xor(m, off);
      const float l2 = __shfl_xor(l, off);
      const float mn = fmaxf(m, m2);
      l = l * __expf(m - mn) + l2 * __expf(m2 - mn);
      m = mn;
    }
    m_run[r] = m; l_run[r] = l;
    u_[r] = 1000.0f / l;
  }

  // ---- pass 2: split-bf16 scores -> weights -> PV ---------------------------
  f32x4 y[8];
#pragma unroll
  for (int dt = 0; dt < 8; ++dt) y[dt] = (f32x4){0.f, 0.f, 0.f, 0.f};
  float W_run[4] = {0.f, 0.f, 0.f, 0.f};

  for (int kc = 0; kc < NKC; ++kc) {
    const int k0 = kc * KB;
    __syncthreads();
    {
      const float* kp = Kg + bh + (size_t)k0 * D_;
      const float* vp = Vg + bh + (size_t)k0 * D_;
#pragma unroll
      for (int p = 0; p < 8; ++p) {
        const int j = tid + p * 256;
        const int row = j >> 5, c4 = j & 31;
        f32x4 v = *(const f32x4*)(kp + (size_t)row * D_ + c4 * 4);
        s16x4 hv, lv;
#pragma unroll
        for (int i = 0; i < 4; ++i) {
          const unsigned short hb = f2bf(v[i]);
          hv[i] = (short)hb;
          lv[i] = (short)f2bf(v[i] - bf2f(hb));
        }
        const int e = (c4 * 4) ^ ((row & 7) << 3);
        *(s16x4*)&khi[row][e] = hv;
        *(s16x4*)&klo[row][e] = lv;
        f32x4 vv = *(const f32x4*)(vp + (size_t)row * D_ + c4 * 4);
#pragma unroll
        for (int i = 0; i < 4; ++i) {
          const int d = c4 * 4 + i;
          vts[d][row ^ ((d & 7) << 3)] = f2bf(vv[i]);  // transposed store
        }
      }
    }
    __syncthreads();

    f32x4 sc[4];
#pragma unroll
    for (int nt = 0; nt < 4; ++nt) sc[nt] = (f32x4){0.f, 0.f, 0.f, 0.f};
#pragma unroll
    for (int s = 0; s < 4; ++s) {
#pragma unroll
      for (int nt = 0; nt < 4; ++nt) {
        const int kr = nt * 16 + lr;
        const int e = (s * 32 + lg * 8) ^ ((kr & 7) << 3);
        s16x8 bh16 = *(const s16x8*)&khi[kr][e];
        s16x8 bl16 = *(const s16x8*)&klo[kr][e];
        sc[nt] = __builtin_amdgcn_mfma_f32_16x16x32_bf16(qhi[s], bh16, sc[nt], 0, 0, 0);
        sc[nt] = __builtin_amdgcn_mfma_f32_16x16x32_bf16(qlo[s], bh16, sc[nt], 0, 0, 0);
        sc[nt] = __builtin_amdgcn_mfma_f32_16x16x32_bf16(qhi[s], bl16, sc[nt], 0, 0, 0);
      }
    }

    // weights; w in [e^-u, 1] -> bf16-safe, exponent max is exactly 0
#pragma unroll
    for (int nt = 0; nt < 4; ++nt) {
#pragma unroll
      for (int r = 0; r < 4; ++r) {
        const float s = sc[nt][r] * SCALE;
        const float p = __expf(s - m_run[r]);
        const float w = __expf(u_[r] * (p - 1.0f));
        W_run[r] += w;
        const int qr = lg * 4 + r;
        wls[wid * 16 + qr][(nt * 16 + lr) ^ ((qr & 7) << 3)] = f2bf(w);
      }
    }

    // PV: A = w-tile rows (same-wave LDS dep), B = transposed V
#pragma unroll
    for (int ks = 0; ks < 2; ++ks) {
      const int e = (ks * 32 + lg * 8) ^ ((lr & 7) << 3);
      s16x8 af = *(const s16x8*)&wls[wid * 16 + lr][e];
#pragma unroll
      for (int dt = 0; dt < 8; ++dt) {
        const int d = dt * 16 + lr;
        const int ev = (ks * 32 + lg * 8) ^ ((d & 7) << 3);
        s16x8 vf = *(const s16x8*)&vts[d][ev];
        y[dt] = __builtin_amdgcn_mfma_f32_16x16x32_bf16(af, vf, y[dt], 0, 0, 0);
      }
    }
  }

  // normalize by sum(w) (reduced over the 16 column-lanes) and store
#pragma unroll
  for (int r = 0; r < 4; ++r) {
    float Wv = W_run[r];
#pragma unroll
    for (int off = 1; off < 16; off <<= 1) Wv += __shfl_xor(Wv, off);
    W_run[r] = 1.0f / Wv;
  }

  float* op = Og + bh + (size_t)(q0 + wid * 16) * D_;
#pragma unroll
  for (int dt = 0; dt < 8; ++dt) {
#pragma unroll
    for (int r = 0; r < 4; ++r) {
      op[(size_t)(lg * 4 + r) * D_ + dt * 16 + lr] = y[dt][r] * W_run[r];
    }
  }
}

extern "C" void kernel_launch(void* const* d_in, const int* in_sizes, int n_in,
                              void* d_out, int out_size, void* d_ws, size_t ws_size,
                              hipStream_t stream) {
  (void)in_sizes; (void)n_in; (void)d_ws; (void)ws_size; (void)out_size;
  const float* Q = (const float*)d_in[0];
  const float* K = (const float*)d_in[1];
  const float* V = (const float*)d_in[2];
  float* O = (float*)d_out;
  dim3 grid(NB * NH * (T_ / BQ));  // 1024 workgroups, 4 waves each
  simattn_fused<<<grid, 256, 0, stream>>>(Q, K, V, O);
}